// Round 3
// baseline (2126.106 us; speedup 1.0000x reference)
//
#include <hip/hip_runtime.h>
#include <math.h>

// Problem constants: B=8, Tt=16, C=1, H=W=512, 4 in-channels, 10 T-planes.
#define Bd 8
#define Td 16
#define Hd 512
#define Wd 512
#define HWc (Hd * Wd)          // 262144
#define NPIX (Bd * HWc)        // 2,097,152

// Fused-step tiling
#define TS   64                // output tile edge
#define HALO 6                 // 6 fused steps -> halo 6
#define RS   (TS + 2 * HALO)   // 76: staged region edge
#define RPAD (RS + 1)          // 77: LDS row pitch (conflict padding)

// ---------------------------------------------------------------------------
// Kernel 1: T = conv2d(x[:, -4:, 0], W_unet, SAME) + b_unet
// ---------------------------------------------------------------------------
__global__ void conv_T_kernel(const float* __restrict__ x,
                              const float* __restrict__ Wu,
                              const float* __restrict__ bu,
                              float* __restrict__ T) {
    __shared__ float sW[370];
    for (int idx = threadIdx.x; idx < 370; idx += blockDim.x)
        sW[idx] = (idx < 360) ? Wu[idx] : bu[idx - 360];
    __syncthreads();

    int n = blockIdx.x * blockDim.x + threadIdx.x;
    if (n >= NPIX) return;
    int b   = n >> 18;
    int rem = n & (HWc - 1);
    int i   = rem >> 9;
    int j   = rem & (Wd - 1);

    const float* xb = x + ((size_t)b * Td + 12) * HWc;
    float xv[4][3][3];
    #pragma unroll
    for (int c = 0; c < 4; ++c)
        #pragma unroll
        for (int kh = 0; kh < 3; ++kh) {
            int ii = i + kh - 1;
            bool iv = (ii >= 0) && (ii < Hd);
            #pragma unroll
            for (int kw = 0; kw < 3; ++kw) {
                int jj = j + kw - 1;
                bool jv = (jj >= 0) && (jj < Wd);
                xv[c][kh][kw] = (iv && jv) ? xb[(size_t)c * HWc + ii * Wd + jj] : 0.0f;
            }
        }

    float* Tb = T + (size_t)b * 10 * HWc + rem;
    #pragma unroll
    for (int o = 0; o < 10; ++o) {
        float acc = sW[360 + o];
        #pragma unroll
        for (int c = 0; c < 4; ++c)
            #pragma unroll
            for (int kh = 0; kh < 3; ++kh)
                #pragma unroll
                for (int kw = 0; kw < 3; ++kw)
                    acc += xv[c][kh][kw] * sW[((o * 4 + c) * 3 + kh) * 3 + kw];
        Tb[(size_t)o * HWc] = acc;
    }
}

// ---------------------------------------------------------------------------
// Kernel 2: single stencil step (used once for xt0).
// out[b,i,j] = T9 + sum_{di,dj} x[b, i+di-1, j+dj-1] * T[dj*3+di]
// ---------------------------------------------------------------------------
__global__ void step0_kernel(const float* __restrict__ xin,   // x slice 15, bstride Td*HWc
                             const float* __restrict__ T,
                             float* __restrict__ xout) {      // out slot 0, bstride Td*HWc
    int n = blockIdx.x * blockDim.x + threadIdx.x;
    if (n >= NPIX) return;
    int b   = n >> 18;
    int rem = n & (HWc - 1);
    int i   = rem >> 9;
    int j   = rem & (Wd - 1);

    const float* xb = xin + (size_t)b * Td * HWc;
    const float* Tb = T + (size_t)b * 10 * HWc + rem;

    float acc = Tb[(size_t)9 * HWc];
    #pragma unroll
    for (int dj = 0; dj < 3; ++dj) {
        int jj = j + dj - 1;
        bool jv = (jj >= 0) && (jj < Wd);
        #pragma unroll
        for (int di = 0; di < 3; ++di) {
            int ii = i + di - 1;
            bool iv = (ii >= 0) && (ii < Hd);
            float v = (iv && jv) ? xb[ii * Wd + jj] : 0.0f;
            acc += v * Tb[(size_t)(dj * 3 + di) * HWc];
        }
    }
    xout[(size_t)b * Td * HWc + rem] = acc;
}

// ---------------------------------------------------------------------------
// Kernel 3: one full scan-body iteration = 6 fused stencil steps
// (plain, sigmoid, plain, sigmoid, plain, sigmoid) on a 64x64 tile with
// halo-6 recompute. Intermediates ping-pong in LDS; pixels outside the
// image are forced to 0 every step (matches global zero padding).
// ---------------------------------------------------------------------------
__global__ __launch_bounds__(512)
void fused6_kernel(const float* __restrict__ xin,   // out slot t-1 (bstride Td*HWc)
                   const float* __restrict__ T,
                   float* __restrict__ xout) {      // out slot t   (bstride Td*HWc)
    __shared__ float sA[RS * RPAD];
    __shared__ float sB[RS * RPAD];

    int tile = blockIdx.x;          // 512 = 8 batches * 8x8 tiles
    int b  = tile >> 6;
    int tr = (tile >> 3) & 7;
    int tc = tile & 7;
    int ri = tr * TS - HALO;        // region origin (may be <0 at borders)
    int rj = tc * TS - HALO;

    const float* xb = xin + (size_t)b * Td * HWc;
    const float* Tb = T + (size_t)b * 10 * HWc;

    // Stage input region (zeros outside image).
    for (int idx = threadIdx.x; idx < RS * RS; idx += 512) {
        int r = idx / RS, c = idx - r * RS;
        int gi = ri + r, gj = rj + c;
        float v = 0.0f;
        if ((unsigned)gi < (unsigned)Hd && (unsigned)gj < (unsigned)Wd)
            v = xb[gi * Wd + gj];
        sA[r * RPAD + c] = v;
    }
    __syncthreads();

    float* cur = sA;
    float* nxt = sB;

    #pragma unroll
    for (int s = 1; s <= 6; ++s) {
        const int E = RS - 2 * s;   // compile-time per unrolled iteration
        for (int idx = threadIdx.x; idx < E * E; idx += 512) {
            int rr = idx / E;
            int r = s + rr, c = s + (idx - rr * E);
            int gi = ri + r, gj = rj + c;
            float v = 0.0f;
            if ((unsigned)gi < (unsigned)Hd && (unsigned)gj < (unsigned)Wd) {
                const float* Tp = Tb + gi * Wd + gj;
                float acc = Tp[(size_t)9 * HWc];
                #pragma unroll
                for (int dj = 0; dj < 3; ++dj)
                    #pragma unroll
                    for (int di = 0; di < 3; ++di)
                        acc += cur[(r + di - 1) * RPAD + (c + dj - 1)] *
                               Tp[(size_t)(dj * 3 + di) * HWc];
                if ((s & 1) == 0) acc = 1.0f / (1.0f + __expf(-acc));
                v = acc;
            }
            nxt[r * RPAD + c] = v;
        }
        __syncthreads();
        float* tmp = cur; cur = nxt; nxt = tmp;
    }

    // Write the 64x64 output tile (always fully inside the image).
    float* ob = xout + (size_t)b * Td * HWc;
    for (int idx = threadIdx.x; idx < TS * TS; idx += 512) {
        int r = idx >> 6, c = idx & 63;
        ob[(ri + HALO + r) * Wd + (rj + HALO + c)] = cur[(HALO + r) * RPAD + (HALO + c)];
    }
}

// ---------------------------------------------------------------------------
// Workspace: T only (B*10*H*W fp32 = 80 MB).
// ---------------------------------------------------------------------------
extern "C" void kernel_launch(void* const* d_in, const int* in_sizes, int n_in,
                              void* d_out, int out_size, void* d_ws, size_t ws_size,
                              hipStream_t stream) {
    const float* x  = (const float*)d_in[0];
    const float* Wu = (const float*)d_in[1];
    const float* bu = (const float*)d_in[2];
    float* out = (float*)d_out;
    float* T   = (float*)d_ws;

    const int threads = 256;
    const int blocks  = NPIX / threads;   // 8192

    conv_T_kernel<<<blocks, threads, 0, stream>>>(x, Wu, bu, T);

    // xt0 = step(x[:, 15, 0], T) -> out[:, 0]
    step0_kernel<<<blocks, threads, 0, stream>>>(x + (size_t)15 * HWc, T, out);

    // out[:, t] = body(out[:, t-1]) for t = 1..15
    for (int t = 1; t < Td; ++t)
        fused6_kernel<<<512, 512, 0, stream>>>(out + (size_t)(t - 1) * HWc, T,
                                               out + (size_t)t * HWc);
}

// Round 4
// 777.201 us; speedup vs baseline: 2.7356x; 2.7356x over previous
//
#include <hip/hip_runtime.h>
#include <math.h>

// Problem constants: B=8, Tt=16, C=1, H=W=512, 4 in-channels, 10 T-planes.
#define Bd 8
#define Td 16
#define Hd 512
#define Wd 512
#define HWc (Hd * Wd)          // 262144
#define NPIX (Bd * HWc)        // 2,097,152

// Fused-step tiling: 64x64 output tile, halo 6 (6 fused steps), T in registers.
#define TS   64
#define H6   6
#define RS   (TS + 2 * H6)     // 76
#define RPITCH (RS + 1)        // 77 (bank-conflict pad)
#define NTHR 1024
#define PPT  6                 // ceil(76*76 / 1024)

// ---------------------------------------------------------------------------
// Kernel 1: T = conv2d(x[:, -4:, 0], W_unet, SAME) + b_unet
// T layout: (B, 10, 512, 512) plane-major in workspace.
// ---------------------------------------------------------------------------
__global__ void conv_T_kernel(const float* __restrict__ x,
                              const float* __restrict__ Wu,
                              const float* __restrict__ bu,
                              float* __restrict__ T) {
    __shared__ float sW[370];
    for (int idx = threadIdx.x; idx < 370; idx += blockDim.x)
        sW[idx] = (idx < 360) ? Wu[idx] : bu[idx - 360];
    __syncthreads();

    int n = blockIdx.x * blockDim.x + threadIdx.x;
    if (n >= NPIX) return;
    int b   = n >> 18;
    int rem = n & (HWc - 1);
    int i   = rem >> 9;
    int j   = rem & (Wd - 1);

    const float* xb = x + ((size_t)b * Td + 12) * HWc;
    float xv[4][3][3];
    #pragma unroll
    for (int c = 0; c < 4; ++c)
        #pragma unroll
        for (int kh = 0; kh < 3; ++kh) {
            int ii = i + kh - 1;
            bool iv = (ii >= 0) && (ii < Hd);
            #pragma unroll
            for (int kw = 0; kw < 3; ++kw) {
                int jj = j + kw - 1;
                bool jv = (jj >= 0) && (jj < Wd);
                xv[c][kh][kw] = (iv && jv) ? xb[(size_t)c * HWc + ii * Wd + jj] : 0.0f;
            }
        }

    float* Tb = T + (size_t)b * 10 * HWc + rem;
    #pragma unroll
    for (int o = 0; o < 10; ++o) {
        float acc = sW[360 + o];
        #pragma unroll
        for (int c = 0; c < 4; ++c)
            #pragma unroll
            for (int kh = 0; kh < 3; ++kh)
                #pragma unroll
                for (int kw = 0; kw < 3; ++kw)
                    acc += xv[c][kh][kw] * sW[((o * 4 + c) * 3 + kh) * 3 + kw];
        Tb[(size_t)o * HWc] = acc;
    }
}

// ---------------------------------------------------------------------------
// Kernel 2: single stencil step (xt0 only).
// out[b,i,j] = T9 + sum_{di,dj} x[b, i+di-1, j+dj-1] * T[dj*3+di]
// ---------------------------------------------------------------------------
__global__ void step0_kernel(const float* __restrict__ xin,   // x slice 15
                             const float* __restrict__ T,
                             float* __restrict__ xout) {      // out slot 0
    int n = blockIdx.x * blockDim.x + threadIdx.x;
    if (n >= NPIX) return;
    int b   = n >> 18;
    int rem = n & (HWc - 1);
    int i   = rem >> 9;
    int j   = rem & (Wd - 1);

    const float* xb = xin + (size_t)b * Td * HWc;
    const float* Tb = T + (size_t)b * 10 * HWc + rem;

    float acc = Tb[(size_t)9 * HWc];
    #pragma unroll
    for (int dj = 0; dj < 3; ++dj) {
        int jj = j + dj - 1;
        bool jv = (jj >= 0) && (jj < Wd);
        #pragma unroll
        for (int di = 0; di < 3; ++di) {
            int ii = i + di - 1;
            bool iv = (ii >= 0) && (ii < Hd);
            float v = (iv && jv) ? xb[ii * Wd + jj] : 0.0f;
            acc += v * Tb[(size_t)(dj * 3 + di) * HWc];
        }
    }
    xout[(size_t)b * Td * HWc + rem] = acc;
}

// ---------------------------------------------------------------------------
// Kernel 3: one scan-body iteration = 6 fused stencil steps with T held in
// REGISTERS (10 coefs x 6 owned pixels per thread), x ping-pong in LDS.
// Sigmoid at even sub-steps. Out-of-image pixels forced to 0 every step.
// Region ring (r/c == 0 or RS-1) is never written; contamination moves
// <=1 px/step inward, halo 6 keeps the 64x64 core clean.
// ---------------------------------------------------------------------------
__global__ __launch_bounds__(NTHR)
void fused6_regT_kernel(const float* __restrict__ xin,   // out slot t-1 base
                        const float* __restrict__ T,
                        float* __restrict__ xout) {      // out slot t base
    __shared__ float sA[RS * RPITCH];
    __shared__ float sB[RS * RPITCH];

    int tile = blockIdx.x;          // 512 = 8 batches * 8x8 tiles
    int b  = tile >> 6;
    int tr = (tile >> 3) & 7;
    int tc = tile & 7;
    int ri = tr * TS - H6;
    int rj = tc * TS - H6;

    const float* xb = xin + (size_t)b * Td * HWc;
    const float* Tb = T + (size_t)b * 10 * HWc;
    int tid = threadIdx.x;

    float treg[PPT][10];
    int   base[PPT];                // LDS word offset of owned pixel
    bool  inimg[PPT];               // pixel inside the 512x512 image
    bool  inter[PPT];               // pixel interior to the region (writable)

    #pragma unroll
    for (int p = 0; p < PPT; ++p) {
        int m = tid + p * NTHR;
        bool valid = m < RS * RS;
        int mm = valid ? m : 0;
        int r = mm / RS;
        int c = mm - r * RS;
        base[p] = r * RPITCH + c;
        int gi = ri + r, gj = rj + c;
        bool im = valid && ((unsigned)gi < (unsigned)Hd) && ((unsigned)gj < (unsigned)Wd);
        inimg[p] = im;
        inter[p] = valid && (r >= 1) && (r < RS - 1) && (c >= 1) && (c < RS - 1);
        float xv = im ? xb[gi * Wd + gj] : 0.0f;
        if (valid) sA[base[p]] = xv;
        #pragma unroll
        for (int k = 0; k < 10; ++k)
            treg[p][k] = im ? Tb[(size_t)k * HWc + gi * Wd + gj] : 0.0f;
    }
    __syncthreads();

    float* cur = sA;
    float* nxt = sB;

    #pragma unroll
    for (int s = 1; s <= 6; ++s) {
        float nv[PPT];
        #pragma unroll
        for (int p = 0; p < PPT; ++p) {
            nv[p] = 0.0f;
            if (inimg[p] && inter[p]) {
                int bo = base[p];
                float acc = treg[p][9];
                // k = dj*3 + di multiplies x[r+di-1, c+dj-1]
                acc += cur[bo - RPITCH - 1] * treg[p][0];
                acc += cur[bo          - 1] * treg[p][1];
                acc += cur[bo + RPITCH - 1] * treg[p][2];
                acc += cur[bo - RPITCH    ] * treg[p][3];
                acc += cur[bo             ] * treg[p][4];
                acc += cur[bo + RPITCH    ] * treg[p][5];
                acc += cur[bo - RPITCH + 1] * treg[p][6];
                acc += cur[bo          + 1] * treg[p][7];
                acc += cur[bo + RPITCH + 1] * treg[p][8];
                if ((s & 1) == 0) acc = 1.0f / (1.0f + __expf(-acc));
                nv[p] = acc;
            }
        }
        #pragma unroll
        for (int p = 0; p < PPT; ++p)
            if (inter[p]) nxt[base[p]] = nv[p];   // 0 when out-of-image
        __syncthreads();
        float* tmp = cur; cur = nxt; nxt = tmp;
    }

    // After an even number of swaps the result sits in cur (== sA).
    float* ob = xout + (size_t)b * Td * HWc;
    for (int idx = tid; idx < TS * TS; idx += NTHR) {
        int rr = idx >> 6, cc = idx & 63;
        ob[(ri + H6 + rr) * Wd + (rj + H6 + cc)] = cur[(H6 + rr) * RPITCH + (H6 + cc)];
    }
}

// ---------------------------------------------------------------------------
// Workspace: T only (B*10*H*W fp32 = 80 MB).
// ---------------------------------------------------------------------------
extern "C" void kernel_launch(void* const* d_in, const int* in_sizes, int n_in,
                              void* d_out, int out_size, void* d_ws, size_t ws_size,
                              hipStream_t stream) {
    const float* x  = (const float*)d_in[0];
    const float* Wu = (const float*)d_in[1];
    const float* bu = (const float*)d_in[2];
    float* out = (float*)d_out;
    float* T   = (float*)d_ws;

    const int threads = 256;
    const int blocks  = NPIX / threads;   // 8192

    conv_T_kernel<<<blocks, threads, 0, stream>>>(x, Wu, bu, T);

    // xt0 = step(x[:, 15, 0], T) -> out[:, 0]
    step0_kernel<<<blocks, threads, 0, stream>>>(x + (size_t)15 * HWc, T, out);

    // out[:, t] = body(out[:, t-1]) for t = 1..15
    for (int t = 1; t < Td; ++t)
        fused6_regT_kernel<<<512, NTHR, 0, stream>>>(out + (size_t)(t - 1) * HWc, T,
                                                     out + (size_t)t * HWc);
}